// Round 7
// baseline (2588.217 us; speedup 1.0000x reference)
//
#include <hip/hip_runtime.h>
#include <hip/hip_bf16.h>

#define TSEQ  512
#define BATCH 64
#define HIDN  512
#define EMBD  100
#define NWG   64

typedef __attribute__((ext_vector_type(8))) short short8;
typedef __attribute__((ext_vector_type(4))) float f32x4;
typedef unsigned int u32;

// ---- workspace layout (bytes) ----
#define A_OFF   0ull                 // 512*64*512 bf16 = 33,554,432
#define HD_OFF  33554432ull          // raw h: 512*64*512 bf16 = 33,554,432
#define HB_OFF  67108864ull          // h exchange: 2*4grp*16row*512col bf16 = 131,072
#define FLG_OFF 67239936ull          // 64 flags * 64B pad = 4,096
#define KEY_OFF 67244032ull          // 6400 * 4 = 25,600
#define DW_OFF  67269632ull          // 112*512*2 = 114,688
#define ZERO_SPAN 160768ull          // HB + FLG + KEY

static __device__ __forceinline__ unsigned short f2bfbits(float f) {
    u32 u = __float_as_uint(f);
    u32 r = (u + 0x7fffu + ((u >> 16) & 1u)) >> 16;   // round-to-nearest-even
    return (unsigned short)r;
}
static __device__ __forceinline__ float bf2f(unsigned short b) {
    return __uint_as_float(((u32)b) << 16);
}
static __device__ __forceinline__ float sigf(float x) {
    return __builtin_amdgcn_rcpf(1.0f + __expf(-x));
}
static __device__ __forceinline__ float tanhfast(float x) {
    float t = __expf(-2.0f * fabsf(x));               // in (0,1], no overflow
    float r = (1.0f - t) * __builtin_amdgcn_rcpf(1.0f + t);
    return copysignf(r, x);
}

// ---------------- K1: dec_w -> bf16 (padded to 112 rows with zeros) ----------
__global__ void k_dw(const float* __restrict__ dw, unsigned short* __restrict__ dwb) {
    int i = blockIdx.x * 256 + threadIdx.x;            // 57,344 = 112*512
    float v = (i < EMBD * HIDN) ? dw[i] : 0.0f;
    dwb[i] = f2bfbits(v);
}

// ---------------- K2: embedding gather -> bf16 A[t][b][k] --------------------
__global__ void k_embed(const int* __restrict__ x, const float* __restrict__ emb,
                        unsigned short* __restrict__ A) {
    int g = blockIdx.x * 256 + threadIdx.x;            // 2,097,152 = T*B*64
    int k8 = g & 63;
    int bt = g >> 6;                                   // t*64 + b
    int b  = bt & 63;
    int t  = bt >> 6;
    int row = x[b * TSEQ + t];
    const float4* src = reinterpret_cast<const float4*>(emb + (size_t)row * HIDN + k8 * 8);
    float4 v0 = src[0], v1 = src[1];
    short8 s;
    s[0] = (short)f2bfbits(v0.x); s[1] = (short)f2bfbits(v0.y);
    s[2] = (short)f2bfbits(v0.z); s[3] = (short)f2bfbits(v0.w);
    s[4] = (short)f2bfbits(v1.x); s[5] = (short)f2bfbits(v1.y);
    s[6] = (short)f2bfbits(v1.z); s[7] = (short)f2bfbits(v1.w);
    *reinterpret_cast<short8*>(A + (size_t)g * 8) = s;
}

// ---------------- K3: persistent LSTM (recurrence only; BN deferred) --------
// KEY STRUCTURE: the LSTM recurrence is independent per batch row, and the
// (h,c) carry is PRE-BatchNorm h -- so batch is split into 4 INDEPENDENT
// groups of 16 rows x 16 WGs. h-exchange spans only the group's 16 WGs
// (vs 64 before); groups decouple (no global max-of-64 convoy per step).
// WG (g = wg&3, m = wg>>2) owns batch rows g*16..+15, h-cols m*32..+31.
// Wave w: nbw = w&3 = gate {i,f,g,o}, kh = w>>2 = K half (0: x/A, 1: h).
// Weights in registers (128 VGPR/wave, round-3-proven shape).
// Exchange protocol = round-3-proven: sc1 store -> vmcnt(0) ack -> flag
// store -> readers poll 16 flags (one vector load) -> sc1 h loads.
__launch_bounds__(512)
__global__ void k_lstm(const float* __restrict__ wih, const float* __restrict__ whh,
                       const float* __restrict__ bih, const float* __restrict__ bhh,
                       const unsigned short* __restrict__ A,
                       unsigned short* __restrict__ hbuf,
                       unsigned short* __restrict__ hd,
                       u32* __restrict__ flg) {
    const int tid  = threadIdx.x;
    const int wg   = blockIdx.x;
    const int g    = wg & 3;          // group 0..3 (batch rows g*16..+15)
    const int m    = wg >> 2;         // member 0..15 (h-cols m*32..+31)
    const int lane = tid & 63;
    const int w    = tid >> 6;        // wave 0..7
    const int nbw  = w & 3;           // gate index (i,f,g,o)
    const int kh   = w >> 2;          // K half: 0 = x/A, 1 = h

    __shared__ float gbuf[2][16][132];                      // partial gates per kh
    __shared__ __align__(16) unsigned short hstage[2][16][32];

    const int l15 = lane & 15;
    const int lk8 = (lane >> 4) * 8;

    // ---- load static B fragments into registers (once) ----
    const float* wsrc = kh ? whh : wih;
    short8 bfr[16][2];
    #pragma unroll
    for (int kk = 0; kk < 16; ++kk) {
        #pragma unroll
        for (int nb = 0; nb < 2; ++nb) {
            int jrow = nbw * HIDN + m * 32 + nb * 16 + l15;   // row of W [4H, H]
            const float* p = wsrc + (size_t)jrow * HIDN + kk * 32 + lk8;
            short8 bb;
            #pragma unroll
            for (int e = 0; e < 8; ++e) bb[e] = (short)f2bfbits(p[e]);
            bfr[kk][nb] = bb;
        }
    }

    // ---- pointwise-role constants: thread = (row prow, col pcol) ----
    const int prow = tid >> 5;        // 0..15 (local batch row)
    const int pcol = tid & 31;        // 0..31 (local h-col)
    const int jj   = m * 32 + pcol;   // global h-col
    const float bias_i = bih[jj]           + bhh[jj];
    const float bias_f = bih[512 + jj]     + bhh[512 + jj];
    const float bias_g = bih[1024 + jj]    + bhh[1024 + jj];
    const float bias_o = bih[1536 + jj]    + bhh[1536 + jj];
    float c = 0.0f;

    const int arow = g * 16 + l15;    // global batch row for MFMA A-frags
    const u32* fpoll = flg + ((size_t)g * 16 + (lane & 15)) * 16;

    // ---- prologue: gbuf[1] = 0 (h(0)=0); gbuf[0] = A(0) @ Wih^T ----
    {
        float* g1 = &gbuf[1][0][0];
        for (int i = tid; i < 16 * 132; i += 512) g1[i] = 0.0f;
    }
    __syncthreads();
    if (kh == 0) {
        const unsigned short* abase = A + (size_t)arow * HIDN;
        f32x4 a0 = {0.f,0.f,0.f,0.f}, a1 = {0.f,0.f,0.f,0.f};
        #pragma unroll
        for (int kk = 0; kk < 16; ++kk) {
            short8 a = *reinterpret_cast<const short8*>(abase + kk * 32 + lk8);
            a0 = __builtin_amdgcn_mfma_f32_16x16x32_bf16(a, bfr[kk][0], a0, 0, 0, 0);
            a1 = __builtin_amdgcn_mfma_f32_16x16x32_bf16(a, bfr[kk][1], a1, 0, 0, 0);
        }
        #pragma unroll
        for (int r = 0; r < 4; ++r) {
            int crow = (lane >> 4) * 4 + r;
            gbuf[0][crow][nbw * 32 + l15]      = a0[r];
            gbuf[0][crow][nbw * 32 + 16 + l15] = a1[r];
        }
    }
    __syncthreads();

    for (int s = 0; s < TSEQ; ++s) {
        // ---- pointwise: gates(s) -> c, h (critical path; BN deferred) ----
        float gi = gbuf[0][prow][pcol]      + gbuf[1][prow][pcol]      + bias_i;
        float gf = gbuf[0][prow][32 + pcol] + gbuf[1][prow][32 + pcol] + bias_f;
        float gg = gbuf[0][prow][64 + pcol] + gbuf[1][prow][64 + pcol] + bias_g;
        float go = gbuf[0][prow][96 + pcol] + gbuf[1][prow][96 + pcol] + bias_o;
        float iv = sigf(gi), fv = sigf(gf), gv = tanhfast(gg), ov = sigf(go);
        c = fv * c + iv * gv;
        float h = ov * tanhfast(c);
        hstage[s & 1][prow][pcol] = f2bfbits(h);
        __syncthreads();                                        // [A]

        const int last = (s == TSEQ - 1);
        const int sb   = (s + 1) & 1;
        const u32 tgt  = (u32)(s + 1);

        // ---- wave0: publish h (sc1) -> ack -> flag (round-3 ordering) ----
        if (!last && w == 0) {
            int r0 = lane >> 2, pc = (lane & 3) * 8;
            short8 hv = *reinterpret_cast<const short8*>(&hstage[s & 1][r0][pc]);
            unsigned short* dst = hbuf + ((size_t)(sb * 4 + g) * 16 + r0) * HIDN + m * 32 + pc;
            asm volatile("global_store_dwordx4 %0, %1, off sc1" :: "v"(dst), "v"(hv) : "memory");
            asm volatile("s_waitcnt vmcnt(0)" ::: "memory");
            if (lane == 0) {
                const u32* myf = flg + ((size_t)g * 16 + m) * 16;
                asm volatile("global_store_dword %0, %1, off sc1" :: "v"(myf), "v"(tgt) : "memory");
            }
        }

        // ---- wave1: drain raw h(s) to hd (for deferred BN+decode) ----
        if (w == 1) {
            int r0 = lane >> 2, pc = (lane & 3) * 8;
            short8 dv = *reinterpret_cast<const short8*>(&hstage[s & 1][r0][pc]);
            *reinterpret_cast<short8*>(
                hd + ((size_t)s * 64 + g * 16 + r0) * HIDN + m * 32 + pc) = dv;
        }

        // ---- MFMA for gates(s+1) ----
        if (!last) {
            if (kh == 0) {
                const unsigned short* abase = A + ((size_t)(s + 1) * 64 + arow) * HIDN;
                f32x4 a0 = {0.f,0.f,0.f,0.f}, a1 = {0.f,0.f,0.f,0.f};
                #pragma unroll
                for (int kk = 0; kk < 16; ++kk) {
                    short8 a = *reinterpret_cast<const short8*>(abase + kk * 32 + lk8);
                    a0 = __builtin_amdgcn_mfma_f32_16x16x32_bf16(a, bfr[kk][0], a0, 0, 0, 0);
                    a1 = __builtin_amdgcn_mfma_f32_16x16x32_bf16(a, bfr[kk][1], a1, 0, 0, 0);
                }
                #pragma unroll
                for (int r = 0; r < 4; ++r) {
                    int crow = (lane >> 4) * 4 + r;
                    gbuf[0][crow][nbw * 32 + l15]      = a0[r];
                    gbuf[0][crow][nbw * 32 + 16 + l15] = a1[r];
                }
            } else {
                // poll the group's 16 flags (lane&15 -> member), then load h
                u32 v;
                do {
                    asm volatile("global_load_dword %0, %1, off sc1"
                                 : "=v"(v) : "v"(fpoll) : "memory");
                    asm volatile("s_waitcnt vmcnt(0)" ::: "memory");
                } while (!__all((int)(v >= tgt)));
                __builtin_amdgcn_sched_barrier(0);
                const unsigned short* hbase = hbuf + ((size_t)(sb * 4 + g) * 16 + l15) * HIDN;
                short8 hf[16];
                #pragma unroll
                for (int kk = 0; kk < 16; ++kk) {
                    const unsigned short* p = hbase + kk * 32 + lk8;
                    asm volatile("global_load_dwordx4 %0, %1, off sc1"
                                 : "=v"(hf[kk]) : "v"(p) : "memory");
                }
                asm volatile("s_waitcnt vmcnt(0)" ::: "memory");
                __builtin_amdgcn_sched_barrier(0);
                f32x4 a0 = {0.f,0.f,0.f,0.f}, a1 = {0.f,0.f,0.f,0.f};
                #pragma unroll
                for (int kk = 0; kk < 16; ++kk) {
                    a0 = __builtin_amdgcn_mfma_f32_16x16x32_bf16(hf[kk], bfr[kk][0], a0, 0, 0, 0);
                    a1 = __builtin_amdgcn_mfma_f32_16x16x32_bf16(hf[kk], bfr[kk][1], a1, 0, 0, 0);
                }
                #pragma unroll
                for (int r = 0; r < 4; ++r) {
                    int crow = (lane >> 4) * 4 + r;
                    gbuf[1][crow][nbw * 32 + l15]      = a0[r];
                    gbuf[1][crow][nbw * 32 + 16 + l15] = a1[r];
                }
            }
        }
        __syncthreads();                                        // [B]
    }
}

// ---------------- K4: deferred BN + dropout + decode GEMM + max -------------
// One WG (256 thr) per t. BN stats over the FULL batch of 64 (exact
// reference semantics), normalize+mask in LDS, then MFMA decode + atomicMax.
__launch_bounds__(256)
__global__ void k_bnd(const unsigned short* __restrict__ hd,
                      const unsigned short* __restrict__ dwb,
                      const float* __restrict__ gamma, const float* __restrict__ beta,
                      const float* __restrict__ mask,
                      u32* __restrict__ key) {
    const int t   = blockIdx.x;
    const int tid = threadIdx.x;
    __shared__ __align__(16) unsigned short hs[64][520];    // 520: 16B-aligned rows

    // phase 1: load h[t] (64x512 bf16) into LDS
    for (int ch = tid; ch < 4096; ch += 256) {
        int row = ch >> 6, c8 = (ch & 63) * 8;
        short8 v = *reinterpret_cast<const short8*>(hd + ((size_t)t * 64 + row) * HIDN + c8);
        *reinterpret_cast<short8*>(&hs[row][c8]) = v;
    }
    __syncthreads();

    // phase 2: BN (biased var over batch) + locked dropout; thread owns 2 cols
    {
        int c0 = tid * 2;
        float s10 = 0.f, s20 = 0.f, s11 = 0.f, s21 = 0.f;
        for (int r = 0; r < 64; ++r) {
            float x0 = bf2f(hs[r][c0]), x1 = bf2f(hs[r][c0 + 1]);
            s10 += x0; s20 += x0 * x0;
            s11 += x1; s21 += x1 * x1;
        }
        float mu0 = s10 * (1.0f / 64.0f), var0 = s20 * (1.0f / 64.0f) - mu0 * mu0;
        float mu1 = s11 * (1.0f / 64.0f), var1 = s21 * (1.0f / 64.0f) - mu1 * mu1;
        float sc0 = gamma[c0]     * rsqrtf(var0 + 1e-5f);
        float sc1 = gamma[c0 + 1] * rsqrtf(var1 + 1e-5f);
        float sh0 = beta[c0]     - mu0 * sc0;
        float sh1 = beta[c0 + 1] - mu1 * sc1;
        for (int r = 0; r < 64; ++r) {
            float2 mk = *reinterpret_cast<const float2*>(&mask[(size_t)r * HIDN + c0]);
            float y0 = (bf2f(hs[r][c0])     * sc0 + sh0) * mk.x * (1.0f / 0.7f);
            float y1 = (bf2f(hs[r][c0 + 1]) * sc1 + sh1) * mk.y * (1.0f / 0.7f);
            hs[r][c0]     = f2bfbits(y0);
            hs[r][c0 + 1] = f2bfbits(y1);
        }
    }
    __syncthreads();

    // phase 3: decode GEMM [64,512]@[512,112] + order-preserving atomicMax
    const int lane = tid & 63;
    const int w    = tid >> 6;
    const int l15  = lane & 15;
    const int lk8  = (lane >> 4) * 8;
    f32x4 acc[7];
    #pragma unroll
    for (int nb = 0; nb < 7; ++nb) acc[nb] = (f32x4){0.f, 0.f, 0.f, 0.f};
    #pragma unroll
    for (int kk = 0; kk < 16; ++kk) {
        short8 a = *reinterpret_cast<const short8*>(&hs[w * 16 + l15][kk * 32 + lk8]);
        #pragma unroll
        for (int nb = 0; nb < 7; ++nb) {
            short8 b = *reinterpret_cast<const short8*>(
                dwb + (size_t)(nb * 16 + l15) * HIDN + kk * 32 + lk8);
            acc[nb] = __builtin_amdgcn_mfma_f32_16x16x32_bf16(a, b, acc[nb], 0, 0, 0);
        }
    }
    #pragma unroll
    for (int nb = 0; nb < 7; ++nb) {
        int n = nb * 16 + l15;
        if (n < EMBD) {
            #pragma unroll
            for (int r = 0; r < 4; ++r) {
                int b = w * 16 + (lane >> 4) * 4 + r;
                u32 u  = __float_as_uint(acc[nb][r]);
                u32 kv = (u & 0x80000000u) ? ~u : (u | 0x80000000u);
                atomicMax(&key[b * EMBD + n], kv);
            }
        }
    }
}

// ---------------- K5: inverse transform + decoder bias -----------------------
__global__ void k_final(const u32* __restrict__ key, const float* __restrict__ db,
                        float* __restrict__ out) {
    int i = blockIdx.x * 256 + threadIdx.x;
    if (i < BATCH * EMBD) {
        u32 k = key[i];
        u32 u = (k & 0x80000000u) ? (k & 0x7fffffffu) : ~k;
        out[i] = __uint_as_float(u) + db[i % EMBD];
    }
}

extern "C" void kernel_launch(void* const* d_in, const int* in_sizes, int n_in,
                              void* d_out, int out_size, void* d_ws, size_t ws_size,
                              hipStream_t stream) {
    const int*   x   = (const int*)d_in[0];
    const float* emb = (const float*)d_in[1];
    const float* wih = (const float*)d_in[2];
    const float* whh = (const float*)d_in[3];
    const float* bih = (const float*)d_in[4];
    const float* bhh = (const float*)d_in[5];
    const float* gam = (const float*)d_in[6];
    const float* bet = (const float*)d_in[7];
    const float* dw  = (const float*)d_in[8];
    const float* db  = (const float*)d_in[9];
    const float* msk = (const float*)d_in[10];

    char* ws = (char*)d_ws;
    unsigned short* A   = (unsigned short*)(ws + A_OFF);
    unsigned short* hd  = (unsigned short*)(ws + HD_OFF);
    unsigned short* hb  = (unsigned short*)(ws + HB_OFF);
    u32*            flg = (u32*)(ws + FLG_OFF);
    u32*            key = (u32*)(ws + KEY_OFF);
    unsigned short* dwb = (unsigned short*)(ws + DW_OFF);

    hipMemsetAsync(ws + HB_OFF, 0, ZERO_SPAN, stream);      // hbuf + flags + keys
    k_dw    <<<224,  256, 0, stream>>>(dw, dwb);
    k_embed <<<8192, 256, 0, stream>>>(x, emb, A);
    k_lstm  <<<NWG,  512, 0, stream>>>(wih, whh, bih, bhh, A, hb, hd, flg);
    k_bnd   <<<TSEQ, 256, 0, stream>>>(hd, dwb, gam, bet, msk, key);
    k_final <<<25,   256, 0, stream>>>(key, db, (float*)d_out);
}

// Round 8
// 2172.615 us; speedup vs baseline: 1.1913x; 1.1913x over previous
//
#include <hip/hip_runtime.h>
#include <hip/hip_bf16.h>

#define TSEQ  512
#define BATCH 64
#define HIDN  512
#define EMBD  100
#define NWG   64

typedef __attribute__((ext_vector_type(8))) short short8;
typedef __attribute__((ext_vector_type(4))) float f32x4;
typedef unsigned int u32;
typedef __attribute__((ext_vector_type(4))) u32 u32x4;
typedef __attribute__((ext_vector_type(2))) u32 u32x2;

// ---- workspace layout (bytes) ----
#define A_OFF   0ull                 // 512*64*512 bf16 = 33,554,432
#define HD_OFF  33554432ull          // raw h: 512*64*512 bf16 = 33,554,432
#define HB_OFF  67108864ull          // granules: 2*4grp*16row*512 u32 = 262,144
#define FLG_OFF 67371008ull          // 64 flags * 64B pad = 4,096
#define KEY_OFF 67375104ull          // 6400 * 4 = 25,600
#define DW_OFF  67400704ull          // 112*512*2 = 114,688
#define ZERO_SPAN 291840ull          // HB + FLG + KEY

static __device__ __forceinline__ unsigned short f2bfbits(float f) {
    u32 u = __float_as_uint(f);
    u32 r = (u + 0x7fffu + ((u >> 16) & 1u)) >> 16;   // round-to-nearest-even
    return (unsigned short)r;
}
static __device__ __forceinline__ float bf2f(unsigned short b) {
    return __uint_as_float(((u32)b) << 16);
}
static __device__ __forceinline__ float sigf(float x) {
    return __builtin_amdgcn_rcpf(1.0f + __expf(-x));
}
static __device__ __forceinline__ float tanhfast(float x) {
    float t = __expf(-2.0f * fabsf(x));               // in (0,1], no overflow
    float r = (1.0f - t) * __builtin_amdgcn_rcpf(1.0f + t);
    return copysignf(r, x);
}

// ---------------- K1: dec_w -> bf16 (padded to 112 rows with zeros) ----------
__global__ void k_dw(const float* __restrict__ dw, unsigned short* __restrict__ dwb) {
    int i = blockIdx.x * 256 + threadIdx.x;            // 57,344 = 112*512
    float v = (i < EMBD * HIDN) ? dw[i] : 0.0f;
    dwb[i] = f2bfbits(v);
}

// ---------------- K2: embedding gather -> bf16 A[t][b][k] --------------------
__global__ void k_embed(const int* __restrict__ x, const float* __restrict__ emb,
                        unsigned short* __restrict__ A) {
    int g = blockIdx.x * 256 + threadIdx.x;            // 2,097,152 = T*B*64
    int k8 = g & 63;
    int bt = g >> 6;                                   // t*64 + b
    int b  = bt & 63;
    int t  = bt >> 6;
    int row = x[b * TSEQ + t];
    const float4* src = reinterpret_cast<const float4*>(emb + (size_t)row * HIDN + k8 * 8);
    float4 v0 = src[0], v1 = src[1];
    short8 s;
    s[0] = (short)f2bfbits(v0.x); s[1] = (short)f2bfbits(v0.y);
    s[2] = (short)f2bfbits(v0.z); s[3] = (short)f2bfbits(v0.w);
    s[4] = (short)f2bfbits(v1.x); s[5] = (short)f2bfbits(v1.y);
    s[6] = (short)f2bfbits(v1.z); s[7] = (short)f2bfbits(v1.w);
    *reinterpret_cast<short8*>(A + (size_t)g * 8) = s;
}

// ---------------- K3: persistent LSTM (recurrence only; BN deferred) --------
// 4 independent groups (16 batch rows) x 16 WGs (32 h-cols each).
// WG (g = wg&3, m = wg>>2). Wave w: nbw = w&3 = gate, kh = w>>2.
// Exchange (the round-7 3-4 L3-RT chain cut to ~1-2 RT):
//   PRIMARY: self-validating granules u32x4 {2bf16,tag,2bf16,tag} stored sc1
//     fire-and-forget by wave0; waves 4-7 poll-load their 4-row slice
//     (8 x u32x4 = 32 VGPR -- no spill, round-4/6 lesson), validate tags,
//     <=4 bounded retries, strip -> LDS broadcast; consumers ds_read.
//   FALLBACK (liveness, round-3-proven): writer also acks + publishes flag;
//     readers that exhaust retries poll flags then reload (data then valid).
__launch_bounds__(512)
__global__ void k_lstm(const float* __restrict__ wih, const float* __restrict__ whh,
                       const float* __restrict__ bih, const float* __restrict__ bhh,
                       const unsigned short* __restrict__ A,
                       u32* __restrict__ hx,
                       unsigned short* __restrict__ hd,
                       u32* __restrict__ flg) {
    const int tid  = threadIdx.x;
    const int wg   = blockIdx.x;
    const int g    = wg & 3;          // group (batch rows g*16..+15)
    const int m    = wg >> 2;         // member (h-cols m*32..+31)
    const int lane = tid & 63;
    const int w    = tid >> 6;        // wave 0..7
    const int nbw  = w & 3;           // gate index
    const int kh   = w >> 2;          // 0: x/A half, 1: h half

    __shared__ float gbuf[2][16][132];                      // partial gates per kh
    __shared__ __align__(16) unsigned short hstage[2][16][32];
    __shared__ __align__(16) unsigned short h_lds[16][520]; // h(s+1), 16 rows

    const int l15 = lane & 15;
    const int lk8 = (lane >> 4) * 8;

    // ---- static weight fragments in registers (one gate's 32 cols) ----
    const float* wsrc = kh ? whh : wih;
    short8 bfr[16][2];
    #pragma unroll
    for (int kk = 0; kk < 16; ++kk) {
        #pragma unroll
        for (int nb = 0; nb < 2; ++nb) {
            int jrow = nbw * HIDN + m * 32 + nb * 16 + l15;   // row of W [4H, H]
            const float* p = wsrc + (size_t)jrow * HIDN + kk * 32 + lk8;
            short8 bb;
            #pragma unroll
            for (int e = 0; e < 8; ++e) bb[e] = (short)f2bfbits(p[e]);
            bfr[kk][nb] = bb;
        }
    }

    // ---- pointwise-role constants: thread = (row prow, col pcol) ----
    const int prow = tid >> 5;        // 0..15 local batch row
    const int pcol = tid & 31;        // 0..31 local h-col
    const int jj   = m * 32 + pcol;
    const float bias_i = bih[jj]           + bhh[jj];
    const float bias_f = bih[512 + jj]     + bhh[512 + jj];
    const float bias_g = bih[1024 + jj]    + bhh[1024 + jj];
    const float bias_o = bih[1536 + jj]    + bhh[1536 + jj];
    float c = 0.0f;

    const int arow = g * 16 + l15;    // global batch row for A-fragments
    const u32* fpoll = flg + ((size_t)g * 16 + (lane & 15)) * 16;
    // reader (waves 4-7): 4-row slice, 8 granule blocks of 4 cols each
    const int rr   = nbw * 4 + (lane >> 4);   // local row 0..15
    const int lgrp = lane & 15;

    // ---- prologue: gbuf[1] = 0 (h(0)=0); gbuf[0] = A(0) @ Wih^T ----
    {
        float* g1 = &gbuf[1][0][0];
        for (int i = tid; i < 16 * 132; i += 512) g1[i] = 0.0f;
    }
    __syncthreads();
    if (kh == 0) {
        const unsigned short* abase = A + (size_t)arow * HIDN;
        f32x4 a0 = {0.f,0.f,0.f,0.f}, a1 = {0.f,0.f,0.f,0.f};
        #pragma unroll
        for (int kk = 0; kk < 16; ++kk) {
            short8 a = *reinterpret_cast<const short8*>(abase + kk * 32 + lk8);
            a0 = __builtin_amdgcn_mfma_f32_16x16x32_bf16(a, bfr[kk][0], a0, 0, 0, 0);
            a1 = __builtin_amdgcn_mfma_f32_16x16x32_bf16(a, bfr[kk][1], a1, 0, 0, 0);
        }
        #pragma unroll
        for (int r = 0; r < 4; ++r) {
            int crow = (lane >> 4) * 4 + r;
            gbuf[0][crow][nbw * 32 + l15]      = a0[r];
            gbuf[0][crow][nbw * 32 + 16 + l15] = a1[r];
        }
    }
    __syncthreads();

    for (int s = 0; s < TSEQ; ++s) {
        // ---- pointwise: gates(s) -> c, h(s+1) (critical path) ----
        float gi = gbuf[0][prow][pcol]      + gbuf[1][prow][pcol]      + bias_i;
        float gf = gbuf[0][prow][32 + pcol] + gbuf[1][prow][32 + pcol] + bias_f;
        float gg = gbuf[0][prow][64 + pcol] + gbuf[1][prow][64 + pcol] + bias_g;
        float go = gbuf[0][prow][96 + pcol] + gbuf[1][prow][96 + pcol] + bias_o;
        float iv = sigf(gi), fv = sigf(gf), gv = tanhfast(gg), ov = sigf(go);
        c = fv * c + iv * gv;
        float h = ov * tanhfast(c);
        hstage[s & 1][prow][pcol] = f2bfbits(h);
        __syncthreads();                                        // [A]

        const int last = (s == TSEQ - 1);
        const int sb   = (s + 1) & 1;
        const u32 tgt  = (u32)(s + 1);

        // ---- wave0: tagged granule publish (fire-and-forget) + flag ----
        if (!last && w == 0) {
            int row = lane >> 2, c0 = (lane & 3) * 8;           // 8 cols per lane
            const u32* hrow = reinterpret_cast<const u32*>(&hstage[s & 1][row][c0]);
            u32 d0 = hrow[0], d1 = hrow[1], d2 = hrow[2], d3 = hrow[3];
            u32x4 q0 = {d0, tgt, d1, tgt};
            u32x4 q1 = {d2, tgt, d3, tgt};
            u32* dst = hx + (((size_t)sb * 4 + g) * 16 + row) * 512 + m * 32 + (lane & 3) * 8;
            asm volatile("global_store_dwordx4 %0, %1, off sc1" :: "v"(dst), "v"(q0) : "memory");
            asm volatile("global_store_dwordx4 %0, %1, off sc1" :: "v"(dst + 4), "v"(q1) : "memory");
            asm volatile("s_waitcnt vmcnt(0)" ::: "memory");    // ack (for fallback order)
            if (lane == 0) {
                const u32* myf = flg + ((size_t)g * 16 + m) * 16;
                asm volatile("global_store_dword %0, %1, off sc1" :: "v"(myf), "v"(tgt) : "memory");
            }
        }

        // ---- wave1: drain raw h(s) to hd (deferred BN consumes it) ----
        if (w == 1) {
            int r0 = lane >> 2, pc = (lane & 3) * 8;
            short8 dv = *reinterpret_cast<const short8*>(&hstage[s & 1][r0][pc]);
            *reinterpret_cast<short8*>(
                hd + ((size_t)s * 64 + g * 16 + r0) * HIDN + m * 32 + pc) = dv;
        }

        if (!last) {
            if (kh == 0) {
                // ---- A-half MFMA for gates(s+1) (L2-resident stream) ----
                const unsigned short* abase = A + ((size_t)(s + 1) * 64 + arow) * HIDN;
                f32x4 a0 = {0.f,0.f,0.f,0.f}, a1 = {0.f,0.f,0.f,0.f};
                #pragma unroll
                for (int kk = 0; kk < 16; ++kk) {
                    short8 a = *reinterpret_cast<const short8*>(abase + kk * 32 + lk8);
                    a0 = __builtin_amdgcn_mfma_f32_16x16x32_bf16(a, bfr[kk][0], a0, 0, 0, 0);
                    a1 = __builtin_amdgcn_mfma_f32_16x16x32_bf16(a, bfr[kk][1], a1, 0, 0, 0);
                }
                #pragma unroll
                for (int r = 0; r < 4; ++r) {
                    int crow = (lane >> 4) * 4 + r;
                    gbuf[0][crow][nbw * 32 + l15]      = a0[r];
                    gbuf[0][crow][nbw * 32 + 16 + l15] = a1[r];
                }
            } else {
                // ---- granule gather: 4-row slice, tag-validated ----
                const size_t rowbase = (((size_t)sb * 4 + g) * 16 + rr) * 512;
                u32x4 gq[8];
                #pragma unroll
                for (int q = 0; q < 8; ++q) {
                    const u32* p = hx + rowbase + (q * 16 + lgrp) * 4;
                    asm volatile("global_load_dwordx4 %0, %1, off sc1"
                                 : "=v"(gq[q]) : "v"(p) : "memory");
                }
                asm volatile("s_waitcnt vmcnt(0)" ::: "memory");
                __builtin_amdgcn_sched_barrier(0);
                int ok;
                {
                    int o = 1;
                    #pragma unroll
                    for (int q = 0; q < 8; ++q) o &= (gq[q].y == tgt) & (gq[q].w == tgt);
                    ok = __all(o);
                }
                #pragma unroll 1
                for (int att = 0; att < 4 && !ok; ++att) {
                    #pragma unroll
                    for (int q = 0; q < 8; ++q) {
                        const u32* p = hx + rowbase + (q * 16 + lgrp) * 4;
                        asm volatile("global_load_dwordx4 %0, %1, off sc1"
                                     : "=v"(gq[q]) : "v"(p) : "memory");
                    }
                    asm volatile("s_waitcnt vmcnt(0)" ::: "memory");
                    __builtin_amdgcn_sched_barrier(0);
                    int o = 1;
                    #pragma unroll
                    for (int q = 0; q < 8; ++q) o &= (gq[q].y == tgt) & (gq[q].w == tgt);
                    ok = __all(o);
                }
                if (!ok) {
                    // fallback: flag poll (proven liveness), then reload
                    u32 v;
                    do {
                        asm volatile("global_load_dword %0, %1, off sc1"
                                     : "=v"(v) : "v"(fpoll) : "memory");
                        asm volatile("s_waitcnt vmcnt(0)" ::: "memory");
                    } while (!__all((int)(v >= tgt)));
                    __builtin_amdgcn_sched_barrier(0);
                    #pragma unroll
                    for (int q = 0; q < 8; ++q) {
                        const u32* p = hx + rowbase + (q * 16 + lgrp) * 4;
                        asm volatile("global_load_dwordx4 %0, %1, off sc1"
                                     : "=v"(gq[q]) : "v"(p) : "memory");
                    }
                    asm volatile("s_waitcnt vmcnt(0)" ::: "memory");
                    __builtin_amdgcn_sched_barrier(0);
                }
                // strip tags -> LDS broadcast (8B stores, ~2-way banks)
                #pragma unroll
                for (int q = 0; q < 8; ++q) {
                    u32x2 d = {gq[q].x, gq[q].z};
                    *reinterpret_cast<u32x2*>(&h_lds[rr][(q * 16 + lgrp) * 4]) = d;
                }
            }
        }
        __syncthreads();                                        // [C]

        if (!last && kh == 1) {
            // ---- h-half MFMA from LDS fragments ----
            f32x4 a0 = {0.f,0.f,0.f,0.f}, a1 = {0.f,0.f,0.f,0.f};
            #pragma unroll
            for (int kk = 0; kk < 16; ++kk) {
                short8 a = *reinterpret_cast<const short8*>(&h_lds[l15][kk * 32 + lk8]);
                a0 = __builtin_amdgcn_mfma_f32_16x16x32_bf16(a, bfr[kk][0], a0, 0, 0, 0);
                a1 = __builtin_amdgcn_mfma_f32_16x16x32_bf16(a, bfr[kk][1], a1, 0, 0, 0);
            }
            #pragma unroll
            for (int r = 0; r < 4; ++r) {
                int crow = (lane >> 4) * 4 + r;
                gbuf[1][crow][nbw * 32 + l15]      = a0[r];
                gbuf[1][crow][nbw * 32 + 16 + l15] = a1[r];
            }
        }
        __syncthreads();                                        // [B]
    }
}

// ---------------- K4: deferred BN + dropout + decode GEMM + max -------------
__launch_bounds__(256)
__global__ void k_bnd(const unsigned short* __restrict__ hd,
                      const unsigned short* __restrict__ dwb,
                      const float* __restrict__ gamma, const float* __restrict__ beta,
                      const float* __restrict__ mask,
                      u32* __restrict__ key) {
    const int t   = blockIdx.x;
    const int tid = threadIdx.x;
    __shared__ __align__(16) unsigned short hs[64][520];

    for (int ch = tid; ch < 4096; ch += 256) {
        int row = ch >> 6, c8 = (ch & 63) * 8;
        short8 v = *reinterpret_cast<const short8*>(hd + ((size_t)t * 64 + row) * HIDN + c8);
        *reinterpret_cast<short8*>(&hs[row][c8]) = v;
    }
    __syncthreads();

    {
        int c0 = tid * 2;
        float s10 = 0.f, s20 = 0.f, s11 = 0.f, s21 = 0.f;
        for (int r = 0; r < 64; ++r) {
            float x0 = bf2f(hs[r][c0]), x1 = bf2f(hs[r][c0 + 1]);
            s10 += x0; s20 += x0 * x0;
            s11 += x1; s21 += x1 * x1;
        }
        float mu0 = s10 * (1.0f / 64.0f), var0 = s20 * (1.0f / 64.0f) - mu0 * mu0;
        float mu1 = s11 * (1.0f / 64.0f), var1 = s21 * (1.0f / 64.0f) - mu1 * mu1;
        float sc0 = gamma[c0]     * rsqrtf(var0 + 1e-5f);
        float sc1 = gamma[c0 + 1] * rsqrtf(var1 + 1e-5f);
        float sh0 = beta[c0]     - mu0 * sc0;
        float sh1 = beta[c0 + 1] - mu1 * sc1;
        for (int r = 0; r < 64; ++r) {
            float2 mk = *reinterpret_cast<const float2*>(&mask[(size_t)r * HIDN + c0]);
            float y0 = (bf2f(hs[r][c0])     * sc0 + sh0) * mk.x * (1.0f / 0.7f);
            float y1 = (bf2f(hs[r][c0 + 1]) * sc1 + sh1) * mk.y * (1.0f / 0.7f);
            hs[r][c0]     = f2bfbits(y0);
            hs[r][c0 + 1] = f2bfbits(y1);
        }
    }
    __syncthreads();

    const int lane = tid & 63;
    const int w    = tid >> 6;
    const int l15  = lane & 15;
    const int lk8  = (lane >> 4) * 8;
    f32x4 acc[7];
    #pragma unroll
    for (int nb = 0; nb < 7; ++nb) acc[nb] = (f32x4){0.f, 0.f, 0.f, 0.f};
    #pragma unroll
    for (int kk = 0; kk < 16; ++kk) {
        short8 a = *reinterpret_cast<const short8*>(&hs[w * 16 + l15][kk * 32 + lk8]);
        #pragma unroll
        for (int nb = 0; nb < 7; ++nb) {
            short8 b = *reinterpret_cast<const short8*>(
                dwb + (size_t)(nb * 16 + l15) * HIDN + kk * 32 + lk8);
            acc[nb] = __builtin_amdgcn_mfma_f32_16x16x32_bf16(a, b, acc[nb], 0, 0, 0);
        }
    }
    #pragma unroll
    for (int nb = 0; nb < 7; ++nb) {
        int n = nb * 16 + l15;
        if (n < EMBD) {
            #pragma unroll
            for (int r = 0; r < 4; ++r) {
                int b = w * 16 + (lane >> 4) * 4 + r;
                u32 u  = __float_as_uint(acc[nb][r]);
                u32 kv = (u & 0x80000000u) ? ~u : (u | 0x80000000u);
                atomicMax(&key[b * EMBD + n], kv);
            }
        }
    }
}

// ---------------- K5: inverse transform + decoder bias -----------------------
__global__ void k_final(const u32* __restrict__ key, const float* __restrict__ db,
                        float* __restrict__ out) {
    int i = blockIdx.x * 256 + threadIdx.x;
    if (i < BATCH * EMBD) {
        u32 k = key[i];
        u32 u = (k & 0x80000000u) ? (k & 0x7fffffffu) : ~k;
        out[i] = __uint_as_float(u) + db[i % EMBD];
    }
}

extern "C" void kernel_launch(void* const* d_in, const int* in_sizes, int n_in,
                              void* d_out, int out_size, void* d_ws, size_t ws_size,
                              hipStream_t stream) {
    const int*   x   = (const int*)d_in[0];
    const float* emb = (const float*)d_in[1];
    const float* wih = (const float*)d_in[2];
    const float* whh = (const float*)d_in[3];
    const float* bih = (const float*)d_in[4];
    const float* bhh = (const float*)d_in[5];
    const float* gam = (const float*)d_in[6];
    const float* bet = (const float*)d_in[7];
    const float* dw  = (const float*)d_in[8];
    const float* db  = (const float*)d_in[9];
    const float* msk = (const float*)d_in[10];

    char* ws = (char*)d_ws;
    unsigned short* A   = (unsigned short*)(ws + A_OFF);
    unsigned short* hd  = (unsigned short*)(ws + HD_OFF);
    u32*            hx  = (u32*)(ws + HB_OFF);
    u32*            flg = (u32*)(ws + FLG_OFF);
    u32*            key = (u32*)(ws + KEY_OFF);
    unsigned short* dwb = (unsigned short*)(ws + DW_OFF);

    hipMemsetAsync(ws + HB_OFF, 0, ZERO_SPAN, stream);      // granules + flags + keys
    k_dw    <<<224,  256, 0, stream>>>(dw, dwb);
    k_embed <<<8192, 256, 0, stream>>>(x, emb, A);
    k_lstm  <<<NWG,  512, 0, stream>>>(wih, whh, bih, bhh, A, hx, hd, flg);
    k_bnd   <<<TSEQ, 256, 0, stream>>>(hd, dwb, gam, bet, msk, key);
    k_final <<<25,   256, 0, stream>>>(key, db, (float*)d_out);
}